// Round 3
// baseline (1640.025 us; speedup 1.0000x reference)
//
#include <hip/hip_runtime.h>
#include <stdint.h>

#define NN 50000
#define NE 800000
#define HID 128
#define NG 500
#define NL 7

typedef short bf16x8 __attribute__((ext_vector_type(8)));
typedef float f32x4 __attribute__((ext_vector_type(4)));

__device__ __forceinline__ unsigned short f2bf(float f) {
  unsigned int u = __builtin_bit_cast(unsigned int, f);
  u += 0x7FFFu + ((u >> 16) & 1u);
  return (unsigned short)(u >> 16);
}
__device__ __forceinline__ float bf2f(unsigned short h) {
  unsigned int u = ((unsigned int)h) << 16;
  return __builtin_bit_cast(float, u);
}

// ---- degree histogram ----
__global__ void k_deg(const int* __restrict__ dst, int* __restrict__ deg) {
  int e = blockIdx.x * 256 + threadIdx.x;
  if (e < NE) atomicAdd(&deg[dst[e]], 1);
}

// ---- exclusive scan (3 kernels) ----
__global__ void k_scan1(const int* __restrict__ deg, int* __restrict__ offs,
                        int* __restrict__ bsum) {
  int i = blockIdx.x * 256 + threadIdx.x;
  int v = (i < NN) ? deg[i] : 0;
  int lane = threadIdx.x & 63, wv = threadIdx.x >> 6;
  int x = v;
  #pragma unroll
  for (int d = 1; d < 64; d <<= 1) {
    int y = __shfl_up(x, d, 64);
    if (lane >= d) x += y;
  }
  __shared__ int wsum[4];
  if (lane == 63) wsum[wv] = x;
  __syncthreads();
  if (threadIdx.x == 0) {
    int s = 0;
    for (int k = 0; k < 4; k++) { int t = wsum[k]; wsum[k] = s; s += t; }
    bsum[blockIdx.x] = s;
  }
  __syncthreads();
  if (i < NN) offs[i] = x - v + wsum[wv];
}

__global__ void k_scan2(int* __restrict__ bsum, int nb) {
  int i = threadIdx.x;
  int v = (i < nb) ? bsum[i] : 0;
  int lane = threadIdx.x & 63, wv = threadIdx.x >> 6;
  int x = v;
  #pragma unroll
  for (int d = 1; d < 64; d <<= 1) {
    int y = __shfl_up(x, d, 64);
    if (lane >= d) x += y;
  }
  __shared__ int wsum[4];
  if (lane == 63) wsum[wv] = x;
  __syncthreads();
  if (threadIdx.x == 0) {
    int s = 0;
    for (int k = 0; k < 4; k++) { int t = wsum[k]; wsum[k] = s; s += t; }
  }
  __syncthreads();
  if (i < nb) bsum[i] = x - v + wsum[wv];
}

__global__ void k_scan3(const int* __restrict__ deg, int* __restrict__ offs,
                        const int* __restrict__ bsum, float* __restrict__ invd) {
  int i = blockIdx.x * 256 + threadIdx.x;
  if (i < NN) {
    offs[i] += bsum[blockIdx.x];
    int d = deg[i];
    invd[i] = 1.0f / (float)(d > 0 ? d : 1);
    if (i == 0) offs[NN] = NE;
  }
}

// ---- CSR fill ----
__global__ void k_fill(const int* __restrict__ src, const int* __restrict__ dst,
                       const int* __restrict__ offs, int* __restrict__ cur,
                       int* __restrict__ csr) {
  int e = blockIdx.x * 256 + threadIdx.x;
  if (e < NE) {
    int d = dst[e];
    int p = atomicAdd(&cur[d], 1);
    csr[offs[d] + p] = src[e];
  }
}

// ---- x (fp32) -> h (bf16) ----
__global__ void k_cvt(const float* __restrict__ x, unsigned short* __restrict__ h) {
  int i = blockIdx.x * 256 + threadIdx.x;
  if (i < NN * HID / 4) {
    float4 v = ((const float4*)x)[i];
    ushort4 r;
    r.x = f2bf(v.x); r.y = f2bf(v.y); r.z = f2bf(v.z); r.w = f2bf(v.w);
    ((ushort4*)h)[i] = r;
  }
}

// ---- weight swizzle (fp32 -> hi/lo bf16 planes, MFMA B-fragment order) ----
// chunk c (0..7) per layer: c<4 -> Wl k-chunk c, c>=4 -> Wr k-chunk c-4
// inner idx = ((t*4+q)*16+i)*8 + j  holds  W[k=cc*32+q*8+j][n=t*16+i]
__global__ void k_swz(const float* __restrict__ Wl, const float* __restrict__ Wr,
                      unsigned short* __restrict__ wswh,
                      unsigned short* __restrict__ wswl) {
  int idx = blockIdx.x * 256 + threadIdx.x;
  if (idx < NL * 2 * 4 * 4096) {
    int j = idx & 7, i = (idx >> 3) & 15, q = (idx >> 7) & 3, t = (idx >> 9) & 7;
    int cc = (idx >> 12) & 3, m = (idx >> 14) & 1, l = idx >> 15;
    int k = cc * 32 + q * 8 + j, n = t * 16 + i;
    const float* W = m ? Wr : Wl;
    float w = W[l * HID * HID + k * HID + n];
    unsigned short hi = f2bf(w);
    unsigned short lo = f2bf(w - bf2f(hi));
    wswh[idx] = hi;
    wswl[idx] = lo;
  }
}

// ---- fused SAGE layer ----
// out_fp -> next h (bf16): relu?( mean_agg(h)@Wl + bl + h@Wr )
// agg in fp32 (split hi/lo for MFMA); W in hi/lo bf16 (near-exact GEMM)
__global__ __launch_bounds__(256) void k_layer(const unsigned short* __restrict__ curh,
                                               const int* __restrict__ offs,
                                               const int* __restrict__ csr,
                                               const float* __restrict__ invd,
                                               const unsigned short* __restrict__ wswh,
                                               const unsigned short* __restrict__ wswl,
                                               const float* __restrict__ bias,
                                               unsigned short* __restrict__ out,
                                               int relu) {
  __shared__ __align__(16) unsigned short sAh[64 * 136];  // agg hi
  __shared__ __align__(16) unsigned short sAl[64 * 136];  // agg lo
  __shared__ __align__(16) unsigned short sH[64 * 136];   // root (exact bf16)
  __shared__ __align__(16) unsigned short sWh[4096];
  __shared__ __align__(16) unsigned short sWl[4096];
  const int tid = threadIdx.x;
  const int lane = tid & 63, wv = tid >> 6;
  const int row0 = blockIdx.x * 64;

  // stage root rows: 64 rows x 16 uint4
  #pragma unroll
  for (int it = 0; it < 4; ++it) {
    int ch = tid + it * 256;
    int r = ch >> 4, u4 = ch & 15;
    int row = row0 + r;
    uint4 v = make_uint4(0u, 0u, 0u, 0u);
    if (row < NN) v = ((const uint4*)(curh + (size_t)row * HID))[u4];
    *(uint4*)&sH[r * 136 + u4 * 8] = v;
  }
  // aggregate: wave wv -> local rows wv*16..+15; lane holds features 2*lane,+1
  for (int rr = 0; rr < 16; ++rr) {
    int r = (wv << 4) + rr;
    int node = row0 + r;
    float ax = 0.f, ay = 0.f;
    if (node < NN) {
      int s = offs[node], e = offs[node + 1];
      int j = s;
      for (; j + 1 < e; j += 2) {
        int u0 = csr[j], u1 = csr[j + 1];
        unsigned int v0 = *(const unsigned int*)(curh + (size_t)u0 * HID + lane * 2);
        unsigned int v1 = *(const unsigned int*)(curh + (size_t)u1 * HID + lane * 2);
        ax += bf2f((unsigned short)(v0 & 0xffff)) + bf2f((unsigned short)(v1 & 0xffff));
        ay += bf2f((unsigned short)(v0 >> 16)) + bf2f((unsigned short)(v1 >> 16));
      }
      if (j < e) {
        int u = csr[j];
        unsigned int v = *(const unsigned int*)(curh + (size_t)u * HID + lane * 2);
        ax += bf2f((unsigned short)(v & 0xffff));
        ay += bf2f((unsigned short)(v >> 16));
      }
      float sc = invd[node];
      ax *= sc; ay *= sc;
    }
    unsigned short xh = f2bf(ax);
    unsigned short yh = f2bf(ay);
    unsigned short xl = f2bf(ax - bf2f(xh));
    unsigned short yl = f2bf(ay - bf2f(yh));
    *(unsigned int*)&sAh[r * 136 + lane * 2] = (unsigned int)xh | ((unsigned int)yh << 16);
    *(unsigned int*)&sAl[r * 136 + lane * 2] = (unsigned int)xl | ((unsigned int)yl << 16);
  }
  __syncthreads();

  f32x4 acc[8];
  #pragma unroll
  for (int t = 0; t < 8; t++) acc[t] = (f32x4){0.f, 0.f, 0.f, 0.f};
  const int mr = (wv << 4) + (lane & 15);
  const int q = lane >> 4;

  for (int c = 0; c < 8; ++c) {
    const uint4* wh = (const uint4*)(wswh + c * 4096);
    const uint4* wl = (const uint4*)(wswl + c * 4096);
    ((uint4*)sWh)[tid] = wh[tid];
    ((uint4*)sWh)[tid + 256] = wh[tid + 256];
    ((uint4*)sWl)[tid] = wl[tid];
    ((uint4*)sWl)[tid + 256] = wl[tid + 256];
    __syncthreads();
    if (c < 4) {
      bf16x8 ahi = *(const bf16x8*)&sAh[mr * 136 + c * 32 + q * 8];
      bf16x8 alo = *(const bf16x8*)&sAl[mr * 136 + c * 32 + q * 8];
      #pragma unroll
      for (int t = 0; t < 8; t++) {
        bf16x8 bh = *(const bf16x8*)&sWh[(t * 4 + q) * 128 + (lane & 15) * 8];
        bf16x8 bl2 = *(const bf16x8*)&sWl[(t * 4 + q) * 128 + (lane & 15) * 8];
        acc[t] = __builtin_amdgcn_mfma_f32_16x16x32_bf16(ahi, bh, acc[t], 0, 0, 0);
        acc[t] = __builtin_amdgcn_mfma_f32_16x16x32_bf16(alo, bh, acc[t], 0, 0, 0);
        acc[t] = __builtin_amdgcn_mfma_f32_16x16x32_bf16(ahi, bl2, acc[t], 0, 0, 0);
      }
    } else {
      bf16x8 a = *(const bf16x8*)&sH[mr * 136 + (c - 4) * 32 + q * 8];
      #pragma unroll
      for (int t = 0; t < 8; t++) {
        bf16x8 bh = *(const bf16x8*)&sWh[(t * 4 + q) * 128 + (lane & 15) * 8];
        bf16x8 bl2 = *(const bf16x8*)&sWl[(t * 4 + q) * 128 + (lane & 15) * 8];
        acc[t] = __builtin_amdgcn_mfma_f32_16x16x32_bf16(a, bh, acc[t], 0, 0, 0);
        acc[t] = __builtin_amdgcn_mfma_f32_16x16x32_bf16(a, bl2, acc[t], 0, 0, 0);
      }
    }
    __syncthreads();
  }

  const int ci = lane & 15;
  const int rb = (wv << 4) + (lane >> 4) * 4;
  #pragma unroll
  for (int t = 0; t < 8; t++) {
    int n = t * 16 + ci;
    float bn = bias[n];
    #pragma unroll
    for (int r2 = 0; r2 < 4; r2++) {
      int row = row0 + rb + r2;
      if (row < NN) {
        float v = acc[t][r2] + bn;
        if (relu) v = fmaxf(v, 0.f);
        out[(size_t)row * HID + n] = f2bf(v);
      }
    }
  }
}

// ---- global add pool (batch sorted -> binary search, no atomics) ----
__global__ void k_pool(const unsigned short* __restrict__ h,
                       const int* __restrict__ batch, float* __restrict__ pooled) {
  int g = blockIdx.x;
  __shared__ int rng[2];
  if (threadIdx.x < 2) {
    int target = g + threadIdx.x;
    int lo = 0, hi = NN;
    while (lo < hi) {
      int mid = (lo + hi) >> 1;
      if (batch[mid] < target) lo = mid + 1; else hi = mid;
    }
    rng[threadIdx.x] = lo;
  }
  __syncthreads();
  int s = rng[0], e = rng[1];
  float a = 0.f;
  for (int r = s; r < e; ++r) a += bf2f(h[(size_t)r * HID + threadIdx.x]);
  pooled[g * HID + threadIdx.x] = a;
}

// ---- final projection 128 -> 2 (all fp32) ----
__global__ void k_out(const float* __restrict__ pooled,
                      const float* __restrict__ Wout,
                      const float* __restrict__ bout,
                      float* __restrict__ out) {
  int g = blockIdx.x;
  int l = threadIdx.x;  // 64
  float a = pooled[g * HID + l], b = pooled[g * HID + 64 + l];
  float p0 = a * Wout[l * 2] + b * Wout[(l + 64) * 2];
  float p1 = a * Wout[l * 2 + 1] + b * Wout[(l + 64) * 2 + 1];
  #pragma unroll
  for (int d = 32; d; d >>= 1) {
    p0 += __shfl_down(p0, d, 64);
    p1 += __shfl_down(p1, d, 64);
  }
  if (l == 0) {
    out[g * 2] = p0 + bout[0];
    out[g * 2 + 1] = p1 + bout[1];
  }
}

extern "C" void kernel_launch(void* const* d_in, const int* in_sizes, int n_in,
                              void* d_out, int out_size, void* d_ws, size_t ws_size,
                              hipStream_t stream) {
  const float* x = (const float*)d_in[0];
  const int* ei = (const int*)d_in[1];
  const int* batch = (const int*)d_in[2];
  const float* Wl = (const float*)d_in[3];
  const float* Wr = (const float*)d_in[4];
  const float* bl = (const float*)d_in[5];
  const float* Wout = (const float*)d_in[6];
  const float* bout = (const float*)d_in[7];
  float* out = (float*)d_out;
  const int* srcE = ei;
  const int* dstE = ei + NE;

  // workspace layout (~31.6 MB total)
  char* w = (char*)d_ws;
  unsigned short* hA = (unsigned short*)w; w += (size_t)NN * HID * 2;  // 12.8MB
  unsigned short* hB = (unsigned short*)w; w += (size_t)NN * HID * 2;  // 12.8MB
  float* invd = (float*)w;   w += (size_t)NN * 4;
  float* pooled = (float*)w; w += (size_t)NG * HID * 4;
  int* deg = (int*)w;  w += (size_t)NN * 4;
  int* cur = (int*)w;  w += (size_t)NN * 4;      // adjacent to deg (one memset)
  int* offs = (int*)w; w += (size_t)50004 * 4;   // NN+1 padded to 16B
  int* csr = (int*)w;  w += (size_t)NE * 4;
  int* bsum = (int*)w; w += 256 * 4;
  unsigned short* wswh = (unsigned short*)w; w += (size_t)NL * 2 * 4 * 4096 * 2;
  unsigned short* wswl = (unsigned short*)w;

  hipMemsetAsync(deg, 0, (size_t)NN * 2 * 4, stream);
  k_deg<<<(NE + 255) / 256, 256, 0, stream>>>(dstE, deg);
  int nb = (NN + 255) / 256;
  k_scan1<<<nb, 256, 0, stream>>>(deg, offs, bsum);
  k_scan2<<<1, 256, 0, stream>>>(bsum, nb);
  k_scan3<<<nb, 256, 0, stream>>>(deg, offs, bsum, invd);
  k_fill<<<(NE + 255) / 256, 256, 0, stream>>>(srcE, dstE, offs, cur, csr);
  k_cvt<<<(NN * HID / 4 + 255) / 256, 256, 0, stream>>>(x, hA);
  k_swz<<<(NL * 2 * 4 * 4096 + 255) / 256, 256, 0, stream>>>(Wl, Wr, wswh, wswl);

  unsigned short* curh = hA;
  unsigned short* nxth = hB;
  for (int l = 0; l < NL; l++) {
    k_layer<<<(NN + 63) / 64, 256, 0, stream>>>(curh, offs, csr, invd,
                                                wswh + (size_t)l * 2 * 4 * 4096,
                                                wswl + (size_t)l * 2 * 4 * 4096,
                                                bl + l * HID, nxth,
                                                (l < NL - 1) ? 1 : 0);
    unsigned short* t = curh; curh = nxth; nxth = t;
  }
  k_pool<<<NG, 128, 0, stream>>>(curh, batch, pooled);
  k_out<<<NG, 64, 0, stream>>>(pooled, Wout, bout, out);
}

// Round 4
// 690.889 us; speedup vs baseline: 2.3738x; 2.3738x over previous
//
#include <hip/hip_runtime.h>
#include <stdint.h>

#define NN 50000
#define NE 800000
#define HID 128
#define NG 500
#define NL 7

typedef short bf16x8 __attribute__((ext_vector_type(8)));
typedef float f32x4 __attribute__((ext_vector_type(4)));

__device__ __forceinline__ unsigned short f2bf(float f) {
  unsigned int u = __builtin_bit_cast(unsigned int, f);
  u += 0x7FFFu + ((u >> 16) & 1u);
  return (unsigned short)(u >> 16);
}
__device__ __forceinline__ float bf2f(unsigned short h) {
  unsigned int u = ((unsigned int)h) << 16;
  return __builtin_bit_cast(float, u);
}
__device__ __forceinline__ float bflo(unsigned int u) {
  return __builtin_bit_cast(float, u << 16);
}
__device__ __forceinline__ float bfhi(unsigned int u) {
  return __builtin_bit_cast(float, u & 0xffff0000u);
}

// ---- degree histogram ----
__global__ void k_deg(const int* __restrict__ dst, int* __restrict__ deg) {
  int e = blockIdx.x * 256 + threadIdx.x;
  if (e < NE) atomicAdd(&deg[dst[e]], 1);
}

// ---- exclusive scan (3 kernels) ----
__global__ void k_scan1(const int* __restrict__ deg, int* __restrict__ offs,
                        int* __restrict__ bsum) {
  int i = blockIdx.x * 256 + threadIdx.x;
  int v = (i < NN) ? deg[i] : 0;
  int lane = threadIdx.x & 63, wv = threadIdx.x >> 6;
  int x = v;
  #pragma unroll
  for (int d = 1; d < 64; d <<= 1) {
    int y = __shfl_up(x, d, 64);
    if (lane >= d) x += y;
  }
  __shared__ int wsum[4];
  if (lane == 63) wsum[wv] = x;
  __syncthreads();
  if (threadIdx.x == 0) {
    int s = 0;
    for (int k = 0; k < 4; k++) { int t = wsum[k]; wsum[k] = s; s += t; }
    bsum[blockIdx.x] = s;
  }
  __syncthreads();
  if (i < NN) offs[i] = x - v + wsum[wv];
}

__global__ void k_scan2(int* __restrict__ bsum, int nb) {
  int i = threadIdx.x;
  int v = (i < nb) ? bsum[i] : 0;
  int lane = threadIdx.x & 63, wv = threadIdx.x >> 6;
  int x = v;
  #pragma unroll
  for (int d = 1; d < 64; d <<= 1) {
    int y = __shfl_up(x, d, 64);
    if (lane >= d) x += y;
  }
  __shared__ int wsum[4];
  if (lane == 63) wsum[wv] = x;
  __syncthreads();
  if (threadIdx.x == 0) {
    int s = 0;
    for (int k = 0; k < 4; k++) { int t = wsum[k]; wsum[k] = s; s += t; }
  }
  __syncthreads();
  if (i < nb) bsum[i] = x - v + wsum[wv];
}

__global__ void k_scan3(const int* __restrict__ deg, int* __restrict__ offs,
                        const int* __restrict__ bsum, float* __restrict__ invd) {
  int i = blockIdx.x * 256 + threadIdx.x;
  if (i < NN) {
    offs[i] += bsum[blockIdx.x];
    int d = deg[i];
    invd[i] = 1.0f / (float)(d > 0 ? d : 1);
    if (i == 0) offs[NN] = NE;
  }
}

// ---- CSR fill ----
__global__ void k_fill(const int* __restrict__ src, const int* __restrict__ dst,
                       const int* __restrict__ offs, int* __restrict__ cur,
                       int* __restrict__ csr) {
  int e = blockIdx.x * 256 + threadIdx.x;
  if (e < NE) {
    int d = dst[e];
    int p = atomicAdd(&cur[d], 1);
    csr[offs[d] + p] = src[e];
  }
}

// ---- x (fp32) -> h (bf16) ----
__global__ void k_cvt(const float* __restrict__ x, unsigned short* __restrict__ h) {
  int i = blockIdx.x * 256 + threadIdx.x;
  if (i < NN * HID / 4) {
    float4 v = ((const float4*)x)[i];
    ushort4 r;
    r.x = f2bf(v.x); r.y = f2bf(v.y); r.z = f2bf(v.z); r.w = f2bf(v.w);
    ((ushort4*)h)[i] = r;
  }
}

// ---- weight swizzle (fp32 -> hi/lo bf16 planes, MFMA B-fragment order) ----
__global__ void k_swz(const float* __restrict__ Wl, const float* __restrict__ Wr,
                      unsigned short* __restrict__ wswh,
                      unsigned short* __restrict__ wswl) {
  int idx = blockIdx.x * 256 + threadIdx.x;
  if (idx < NL * 2 * 4 * 4096) {
    int j = idx & 7, i = (idx >> 3) & 15, q = (idx >> 7) & 3, t = (idx >> 9) & 7;
    int cc = (idx >> 12) & 3, m = (idx >> 14) & 1, l = idx >> 15;
    int k = cc * 32 + q * 8 + j, n = t * 16 + i;
    const float* W = m ? Wr : Wl;
    float w = W[l * HID * HID + k * HID + n];
    unsigned short hi = f2bf(w);
    unsigned short lo = f2bf(w - bf2f(hi));
    wswh[idx] = hi;
    wswl[idx] = lo;
  }
}

// ---- fused SAGE layer ----
// quarter-wave (16 lanes) per node gather, uint4 row segments, index broadcast
__global__ __launch_bounds__(256) void k_layer(const unsigned short* __restrict__ curh,
                                               const int* __restrict__ offs,
                                               const int* __restrict__ csr,
                                               const float* __restrict__ invd,
                                               const unsigned short* __restrict__ wswh,
                                               const unsigned short* __restrict__ wswl,
                                               const float* __restrict__ bias,
                                               unsigned short* __restrict__ out,
                                               int relu) {
  __shared__ __align__(16) unsigned short sA[64 * 136];  // agg (bf16)
  __shared__ __align__(16) unsigned short sH[64 * 136];  // root
  __shared__ __align__(16) unsigned short sWh[4096];
  __shared__ __align__(16) unsigned short sWl[4096];
  const int tid = threadIdx.x;
  const int lane = tid & 63, wv = tid >> 6;
  const int row0 = blockIdx.x * 64;

  // stage root rows: 64 rows x 16 uint4
  #pragma unroll
  for (int it = 0; it < 4; ++it) {
    int ch = tid + it * 256;
    int r = ch >> 4, u4 = ch & 15;
    int row = row0 + r;
    uint4 v = make_uint4(0u, 0u, 0u, 0u);
    if (row < NN) v = ((const uint4*)(curh + (size_t)row * HID))[u4];
    *(uint4*)&sH[r * 136 + u4 * 8] = v;
  }

  // gather: quarter-wave qw (0..15) handles rows qw*4..qw*4+3; lane sl covers
  // features 8*sl..8*sl+7 (16B per edge per lane)
  const int qw = tid >> 4, sl = tid & 15;
  for (int k = 0; k < 4; ++k) {
    int r = qw * 4 + k;
    int node = row0 + r;
    float a0 = 0.f, a1 = 0.f, a2 = 0.f, a3 = 0.f;
    float a4 = 0.f, a5 = 0.f, a6 = 0.f, a7 = 0.f;
    if (node < NN) {
      int s = offs[node], e = offs[node + 1];
      for (int j = s; j < e; j += 16) {
        int idx = 0;
        if (j + sl < e) idx = csr[j + sl];
        int cnt = e - j; if (cnt > 16) cnt = 16;
        int t = 0;
        for (; t + 4 <= cnt; t += 4) {
          int i0 = __shfl(idx, t, 16);
          int i1 = __shfl(idx, t + 1, 16);
          int i2 = __shfl(idx, t + 2, 16);
          int i3 = __shfl(idx, t + 3, 16);
          uint4 v0 = *(const uint4*)(curh + (size_t)i0 * HID + sl * 8);
          uint4 v1 = *(const uint4*)(curh + (size_t)i1 * HID + sl * 8);
          uint4 v2 = *(const uint4*)(curh + (size_t)i2 * HID + sl * 8);
          uint4 v3 = *(const uint4*)(curh + (size_t)i3 * HID + sl * 8);
          a0 += bflo(v0.x); a1 += bfhi(v0.x); a2 += bflo(v0.y); a3 += bfhi(v0.y);
          a4 += bflo(v0.z); a5 += bfhi(v0.z); a6 += bflo(v0.w); a7 += bfhi(v0.w);
          a0 += bflo(v1.x); a1 += bfhi(v1.x); a2 += bflo(v1.y); a3 += bfhi(v1.y);
          a4 += bflo(v1.z); a5 += bfhi(v1.z); a6 += bflo(v1.w); a7 += bfhi(v1.w);
          a0 += bflo(v2.x); a1 += bfhi(v2.x); a2 += bflo(v2.y); a3 += bfhi(v2.y);
          a4 += bflo(v2.z); a5 += bfhi(v2.z); a6 += bflo(v2.w); a7 += bfhi(v2.w);
          a0 += bflo(v3.x); a1 += bfhi(v3.x); a2 += bflo(v3.y); a3 += bfhi(v3.y);
          a4 += bflo(v3.z); a5 += bfhi(v3.z); a6 += bflo(v3.w); a7 += bfhi(v3.w);
        }
        for (; t < cnt; ++t) {
          int i0 = __shfl(idx, t, 16);
          uint4 v0 = *(const uint4*)(curh + (size_t)i0 * HID + sl * 8);
          a0 += bflo(v0.x); a1 += bfhi(v0.x); a2 += bflo(v0.y); a3 += bfhi(v0.y);
          a4 += bflo(v0.z); a5 += bfhi(v0.z); a6 += bflo(v0.w); a7 += bfhi(v0.w);
        }
      }
      float sc = invd[node];
      a0 *= sc; a1 *= sc; a2 *= sc; a3 *= sc;
      a4 *= sc; a5 *= sc; a6 *= sc; a7 *= sc;
    }
    unsigned int w0 = (unsigned int)f2bf(a0) | ((unsigned int)f2bf(a1) << 16);
    unsigned int w1 = (unsigned int)f2bf(a2) | ((unsigned int)f2bf(a3) << 16);
    unsigned int w2 = (unsigned int)f2bf(a4) | ((unsigned int)f2bf(a5) << 16);
    unsigned int w3 = (unsigned int)f2bf(a6) | ((unsigned int)f2bf(a7) << 16);
    *(uint4*)&sA[r * 136 + sl * 8] = make_uint4(w0, w1, w2, w3);
  }
  __syncthreads();

  f32x4 acc[8];
  #pragma unroll
  for (int t = 0; t < 8; t++) acc[t] = (f32x4){0.f, 0.f, 0.f, 0.f};
  const int mr = (wv << 4) + (lane & 15);
  const int q = lane >> 4;

  for (int c = 0; c < 8; ++c) {
    const uint4* wh = (const uint4*)(wswh + c * 4096);
    const uint4* wl = (const uint4*)(wswl + c * 4096);
    ((uint4*)sWh)[tid] = wh[tid];
    ((uint4*)sWh)[tid + 256] = wh[tid + 256];
    ((uint4*)sWl)[tid] = wl[tid];
    ((uint4*)sWl)[tid + 256] = wl[tid + 256];
    __syncthreads();
    const unsigned short* sSrc = (c < 4) ? sA : sH;
    bf16x8 a = *(const bf16x8*)&sSrc[mr * 136 + (c & 3) * 32 + q * 8];
    #pragma unroll
    for (int t = 0; t < 8; t++) {
      bf16x8 bh = *(const bf16x8*)&sWh[(t * 4 + q) * 128 + (lane & 15) * 8];
      bf16x8 bl2 = *(const bf16x8*)&sWl[(t * 4 + q) * 128 + (lane & 15) * 8];
      acc[t] = __builtin_amdgcn_mfma_f32_16x16x32_bf16(a, bh, acc[t], 0, 0, 0);
      acc[t] = __builtin_amdgcn_mfma_f32_16x16x32_bf16(a, bl2, acc[t], 0, 0, 0);
    }
    __syncthreads();
  }

  const int ci = lane & 15;
  const int rb = (wv << 4) + (lane >> 4) * 4;
  #pragma unroll
  for (int t = 0; t < 8; t++) {
    int n = t * 16 + ci;
    float bn = bias[n];
    #pragma unroll
    for (int r2 = 0; r2 < 4; r2++) {
      int row = row0 + rb + r2;
      if (row < NN) {
        float v = acc[t][r2] + bn;
        if (relu) v = fmaxf(v, 0.f);
        out[(size_t)row * HID + n] = f2bf(v);
      }
    }
  }
}

// ---- global add pool (batch sorted -> binary search, no atomics) ----
__global__ void k_pool(const unsigned short* __restrict__ h,
                       const int* __restrict__ batch, float* __restrict__ pooled) {
  int g = blockIdx.x;
  __shared__ int rng[2];
  if (threadIdx.x < 2) {
    int target = g + threadIdx.x;
    int lo = 0, hi = NN;
    while (lo < hi) {
      int mid = (lo + hi) >> 1;
      if (batch[mid] < target) lo = mid + 1; else hi = mid;
    }
    rng[threadIdx.x] = lo;
  }
  __syncthreads();
  int s = rng[0], e = rng[1];
  float a = 0.f;
  for (int r = s; r < e; ++r) a += bf2f(h[(size_t)r * HID + threadIdx.x]);
  pooled[g * HID + threadIdx.x] = a;
}

// ---- final projection 128 -> 2 (all fp32) ----
__global__ void k_out(const float* __restrict__ pooled,
                      const float* __restrict__ Wout,
                      const float* __restrict__ bout,
                      float* __restrict__ out) {
  int g = blockIdx.x;
  int l = threadIdx.x;  // 64
  float a = pooled[g * HID + l], b = pooled[g * HID + 64 + l];
  float p0 = a * Wout[l * 2] + b * Wout[(l + 64) * 2];
  float p1 = a * Wout[l * 2 + 1] + b * Wout[(l + 64) * 2 + 1];
  #pragma unroll
  for (int d = 32; d; d >>= 1) {
    p0 += __shfl_down(p0, d, 64);
    p1 += __shfl_down(p1, d, 64);
  }
  if (l == 0) {
    out[g * 2] = p0 + bout[0];
    out[g * 2 + 1] = p1 + bout[1];
  }
}

extern "C" void kernel_launch(void* const* d_in, const int* in_sizes, int n_in,
                              void* d_out, int out_size, void* d_ws, size_t ws_size,
                              hipStream_t stream) {
  const float* x = (const float*)d_in[0];
  const int* ei = (const int*)d_in[1];
  const int* batch = (const int*)d_in[2];
  const float* Wl = (const float*)d_in[3];
  const float* Wr = (const float*)d_in[4];
  const float* bl = (const float*)d_in[5];
  const float* Wout = (const float*)d_in[6];
  const float* bout = (const float*)d_in[7];
  float* out = (float*)d_out;
  const int* srcE = ei;
  const int* dstE = ei + NE;

  // workspace layout (~31.6 MB total)
  char* w = (char*)d_ws;
  unsigned short* hA = (unsigned short*)w; w += (size_t)NN * HID * 2;
  unsigned short* hB = (unsigned short*)w; w += (size_t)NN * HID * 2;
  float* invd = (float*)w;   w += (size_t)NN * 4;
  float* pooled = (float*)w; w += (size_t)NG * HID * 4;
  int* deg = (int*)w;  w += (size_t)NN * 4;
  int* cur = (int*)w;  w += (size_t)NN * 4;      // adjacent to deg (one memset)
  int* offs = (int*)w; w += (size_t)50004 * 4;
  int* csr = (int*)w;  w += (size_t)NE * 4;
  int* bsum = (int*)w; w += 256 * 4;
  unsigned short* wswh = (unsigned short*)w; w += (size_t)NL * 2 * 4 * 4096 * 2;
  unsigned short* wswl = (unsigned short*)w;

  hipMemsetAsync(deg, 0, (size_t)NN * 2 * 4, stream);
  k_deg<<<(NE + 255) / 256, 256, 0, stream>>>(dstE, deg);
  int nb = (NN + 255) / 256;
  k_scan1<<<nb, 256, 0, stream>>>(deg, offs, bsum);
  k_scan2<<<1, 256, 0, stream>>>(bsum, nb);
  k_scan3<<<nb, 256, 0, stream>>>(deg, offs, bsum, invd);
  k_fill<<<(NE + 255) / 256, 256, 0, stream>>>(srcE, dstE, offs, cur, csr);
  k_cvt<<<(NN * HID / 4 + 255) / 256, 256, 0, stream>>>(x, hA);
  k_swz<<<(NL * 2 * 4 * 4096 + 255) / 256, 256, 0, stream>>>(Wl, Wr, wswh, wswl);

  unsigned short* curh = hA;
  unsigned short* nxth = hB;
  for (int l = 0; l < NL; l++) {
    k_layer<<<(NN + 63) / 64, 256, 0, stream>>>(curh, offs, csr, invd,
                                                wswh + (size_t)l * 2 * 4 * 4096,
                                                wswl + (size_t)l * 2 * 4 * 4096,
                                                bl + l * HID, nxth,
                                                (l < NL - 1) ? 1 : 0);
    unsigned short* t = curh; curh = nxth; nxth = t;
  }
  k_pool<<<NG, 128, 0, stream>>>(curh, batch, pooled);
  k_out<<<NG, 64, 0, stream>>>(pooled, Wout, bout, out);
}

// Round 5
// 606.553 us; speedup vs baseline: 2.7038x; 1.1390x over previous
//
#include <hip/hip_runtime.h>
#include <stdint.h>

#define NN 50000
#define NE 800000
#define HID 128
#define NG 500
#define NL 7

typedef short bf16x8 __attribute__((ext_vector_type(8)));
typedef float f32x4 __attribute__((ext_vector_type(4)));

__device__ __forceinline__ unsigned short f2bf(float f) {
  unsigned int u = __builtin_bit_cast(unsigned int, f);
  u += 0x7FFFu + ((u >> 16) & 1u);
  return (unsigned short)(u >> 16);
}
__device__ __forceinline__ float bf2f(unsigned short h) {
  unsigned int u = ((unsigned int)h) << 16;
  return __builtin_bit_cast(float, u);
}
__device__ __forceinline__ float bflo(unsigned int u) {
  return __builtin_bit_cast(float, u << 16);
}
__device__ __forceinline__ float bfhi(unsigned int u) {
  return __builtin_bit_cast(float, u & 0xffff0000u);
}

// ---- degree histogram ----
__global__ void k_deg(const int* __restrict__ dst, int* __restrict__ deg) {
  int e = blockIdx.x * 256 + threadIdx.x;
  if (e < NE) atomicAdd(&deg[dst[e]], 1);
}

// ---- exclusive scan (3 kernels) ----
__global__ void k_scan1(const int* __restrict__ deg, int* __restrict__ offs,
                        int* __restrict__ bsum) {
  int i = blockIdx.x * 256 + threadIdx.x;
  int v = (i < NN) ? deg[i] : 0;
  int lane = threadIdx.x & 63, wv = threadIdx.x >> 6;
  int x = v;
  #pragma unroll
  for (int d = 1; d < 64; d <<= 1) {
    int y = __shfl_up(x, d, 64);
    if (lane >= d) x += y;
  }
  __shared__ int wsum[4];
  if (lane == 63) wsum[wv] = x;
  __syncthreads();
  if (threadIdx.x == 0) {
    int s = 0;
    for (int k = 0; k < 4; k++) { int t = wsum[k]; wsum[k] = s; s += t; }
    bsum[blockIdx.x] = s;
  }
  __syncthreads();
  if (i < NN) offs[i] = x - v + wsum[wv];
}

__global__ void k_scan2(int* __restrict__ bsum, int nb) {
  int i = threadIdx.x;
  int v = (i < nb) ? bsum[i] : 0;
  int lane = threadIdx.x & 63, wv = threadIdx.x >> 6;
  int x = v;
  #pragma unroll
  for (int d = 1; d < 64; d <<= 1) {
    int y = __shfl_up(x, d, 64);
    if (lane >= d) x += y;
  }
  __shared__ int wsum[4];
  if (lane == 63) wsum[wv] = x;
  __syncthreads();
  if (threadIdx.x == 0) {
    int s = 0;
    for (int k = 0; k < 4; k++) { int t = wsum[k]; wsum[k] = s; s += t; }
  }
  __syncthreads();
  if (i < nb) bsum[i] = x - v + wsum[wv];
}

__global__ void k_scan3(const int* __restrict__ deg, int* __restrict__ offs,
                        const int* __restrict__ bsum, float* __restrict__ invd) {
  int i = blockIdx.x * 256 + threadIdx.x;
  if (i < NN) {
    offs[i] += bsum[blockIdx.x];
    int d = deg[i];
    invd[i] = 1.0f / (float)(d > 0 ? d : 1);
    if (i == 0) offs[NN] = NE;
  }
}

// ---- CSR fill ----
__global__ void k_fill(const int* __restrict__ src, const int* __restrict__ dst,
                       const int* __restrict__ offs, int* __restrict__ cur,
                       int* __restrict__ csr) {
  int e = blockIdx.x * 256 + threadIdx.x;
  if (e < NE) {
    int d = dst[e];
    int p = atomicAdd(&cur[d], 1);
    csr[offs[d] + p] = src[e];
  }
}

// ---- x (fp32) -> h (bf16); also zero the pad row NN of both buffers ----
__global__ void k_cvt(const float* __restrict__ x, unsigned short* __restrict__ hA,
                      unsigned short* __restrict__ hB) {
  int i = blockIdx.x * 256 + threadIdx.x;
  if (i < NN * HID / 4) {
    float4 v = ((const float4*)x)[i];
    ushort4 r;
    r.x = f2bf(v.x); r.y = f2bf(v.y); r.z = f2bf(v.z); r.w = f2bf(v.w);
    ((ushort4*)hA)[i] = r;
  }
  if (i < 32) {
    unsigned short* pad = (i < 16) ? (hA + (size_t)NN * HID) : (hB + (size_t)NN * HID);
    *(uint4*)&pad[(i & 15) * 8] = make_uint4(0u, 0u, 0u, 0u);
  }
}

// ---- weight swizzle (fp32 -> hi/lo bf16 planes, MFMA B-fragment order) ----
__global__ void k_swz(const float* __restrict__ Wl, const float* __restrict__ Wr,
                      unsigned short* __restrict__ wswh,
                      unsigned short* __restrict__ wswl) {
  int idx = blockIdx.x * 256 + threadIdx.x;
  if (idx < NL * 2 * 4 * 4096) {
    int j = idx & 7, i = (idx >> 3) & 15, q = (idx >> 7) & 3, t = (idx >> 9) & 7;
    int cc = (idx >> 12) & 3, m = (idx >> 14) & 1, l = idx >> 15;
    int k = cc * 32 + q * 8 + j, n = t * 16 + i;
    const float* W = m ? Wr : Wl;
    float w = W[l * HID * HID + k * HID + n];
    unsigned short hi = f2bf(w);
    unsigned short lo = f2bf(w - bf2f(hi));
    wswh[idx] = hi;
    wswl[idx] = lo;
  }
}

// ---- fused SAGE layer ----
// gather: quarter-wave per node, full 16-edge strip issued before consumption
__global__ __launch_bounds__(256) void k_layer(const unsigned short* __restrict__ curh,
                                               const int* __restrict__ offs,
                                               const int* __restrict__ csr,
                                               const float* __restrict__ invd,
                                               const unsigned short* __restrict__ wswh,
                                               const unsigned short* __restrict__ wswl,
                                               const float* __restrict__ bias,
                                               unsigned short* __restrict__ out,
                                               int relu) {
  __shared__ __align__(16) unsigned short sA[64 * 136];  // agg (bf16)
  __shared__ __align__(16) unsigned short sH[64 * 136];  // root
  __shared__ __align__(16) unsigned short sWh[4096];
  __shared__ __align__(16) unsigned short sWl[4096];
  const int tid = threadIdx.x;
  const int lane = tid & 63, wv = tid >> 6;
  const int row0 = blockIdx.x * 64;

  // stage root rows: 64 rows x 16 uint4
  #pragma unroll
  for (int it = 0; it < 4; ++it) {
    int ch = tid + it * 256;
    int r = ch >> 4, u4 = ch & 15;
    int row = row0 + r;
    uint4 v = make_uint4(0u, 0u, 0u, 0u);
    if (row < NN) v = ((const uint4*)(curh + (size_t)row * HID))[u4];
    *(uint4*)&sH[r * 136 + u4 * 8] = v;
  }

  // gather: qw (0..15) handles rows qw*4..+3; lane sl covers feats 8*sl..+7
  const int qw = tid >> 4, sl = tid & 15;
  const unsigned short* rowbase = curh + sl * 8;
  for (int k = 0; k < 4; ++k) {
    int r = qw * 4 + k;
    int node = row0 + r;
    float a0 = 0.f, a1 = 0.f, a2 = 0.f, a3 = 0.f;
    float a4 = 0.f, a5 = 0.f, a6 = 0.f, a7 = 0.f;
    float sc = 0.f;
    if (node < NN) {
      sc = invd[node];
      int s = offs[node], e = offs[node + 1];
      for (int j = s; j < e; j += 16) {
        // idx defaults to pad row NN (zeros) for out-of-range slots
        int idx = (j + sl < e) ? csr[j + sl] : NN;
        uint4 v[16];
        #pragma unroll
        for (int t = 0; t < 16; ++t) {
          int it = __shfl(idx, t, 16);
          v[t] = *(const uint4*)(rowbase + (size_t)it * HID);
        }
        #pragma unroll
        for (int t = 0; t < 16; ++t) {
          a0 += bflo(v[t].x); a1 += bfhi(v[t].x);
          a2 += bflo(v[t].y); a3 += bfhi(v[t].y);
          a4 += bflo(v[t].z); a5 += bfhi(v[t].z);
          a6 += bflo(v[t].w); a7 += bfhi(v[t].w);
        }
      }
      a0 *= sc; a1 *= sc; a2 *= sc; a3 *= sc;
      a4 *= sc; a5 *= sc; a6 *= sc; a7 *= sc;
    }
    unsigned int w0 = (unsigned int)f2bf(a0) | ((unsigned int)f2bf(a1) << 16);
    unsigned int w1 = (unsigned int)f2bf(a2) | ((unsigned int)f2bf(a3) << 16);
    unsigned int w2 = (unsigned int)f2bf(a4) | ((unsigned int)f2bf(a5) << 16);
    unsigned int w3 = (unsigned int)f2bf(a6) | ((unsigned int)f2bf(a7) << 16);
    *(uint4*)&sA[r * 136 + sl * 8] = make_uint4(w0, w1, w2, w3);
  }
  __syncthreads();

  f32x4 acc[8];
  #pragma unroll
  for (int t = 0; t < 8; t++) acc[t] = (f32x4){0.f, 0.f, 0.f, 0.f};
  const int mr = (wv << 4) + (lane & 15);
  const int q = lane >> 4;

  for (int c = 0; c < 8; ++c) {
    const uint4* wh = (const uint4*)(wswh + c * 4096);
    const uint4* wl = (const uint4*)(wswl + c * 4096);
    ((uint4*)sWh)[tid] = wh[tid];
    ((uint4*)sWh)[tid + 256] = wh[tid + 256];
    ((uint4*)sWl)[tid] = wl[tid];
    ((uint4*)sWl)[tid + 256] = wl[tid + 256];
    __syncthreads();
    const unsigned short* sSrc = (c < 4) ? sA : sH;
    bf16x8 a = *(const bf16x8*)&sSrc[mr * 136 + (c & 3) * 32 + q * 8];
    #pragma unroll
    for (int t = 0; t < 8; t++) {
      bf16x8 bh = *(const bf16x8*)&sWh[(t * 4 + q) * 128 + (lane & 15) * 8];
      bf16x8 bl2 = *(const bf16x8*)&sWl[(t * 4 + q) * 128 + (lane & 15) * 8];
      acc[t] = __builtin_amdgcn_mfma_f32_16x16x32_bf16(a, bh, acc[t], 0, 0, 0);
      acc[t] = __builtin_amdgcn_mfma_f32_16x16x32_bf16(a, bl2, acc[t], 0, 0, 0);
    }
    __syncthreads();
  }

  const int ci = lane & 15;
  const int rb = (wv << 4) + (lane >> 4) * 4;
  #pragma unroll
  for (int t = 0; t < 8; t++) {
    int n = t * 16 + ci;
    float bn = bias[n];
    #pragma unroll
    for (int r2 = 0; r2 < 4; r2++) {
      int row = row0 + rb + r2;
      if (row < NN) {
        float v = acc[t][r2] + bn;
        if (relu) v = fmaxf(v, 0.f);
        out[(size_t)row * HID + n] = f2bf(v);
      }
    }
  }
}

// ---- global add pool (batch sorted -> binary search, no atomics) ----
__global__ void k_pool(const unsigned short* __restrict__ h,
                       const int* __restrict__ batch, float* __restrict__ pooled) {
  int g = blockIdx.x;
  __shared__ int rng[2];
  if (threadIdx.x < 2) {
    int target = g + threadIdx.x;
    int lo = 0, hi = NN;
    while (lo < hi) {
      int mid = (lo + hi) >> 1;
      if (batch[mid] < target) lo = mid + 1; else hi = mid;
    }
    rng[threadIdx.x] = lo;
  }
  __syncthreads();
  int s = rng[0], e = rng[1];
  float a = 0.f;
  for (int r = s; r < e; ++r) a += bf2f(h[(size_t)r * HID + threadIdx.x]);
  pooled[g * HID + threadIdx.x] = a;
}

// ---- final projection 128 -> 2 (all fp32) ----
__global__ void k_out(const float* __restrict__ pooled,
                      const float* __restrict__ Wout,
                      const float* __restrict__ bout,
                      float* __restrict__ out) {
  int g = blockIdx.x;
  int l = threadIdx.x;  // 64
  float a = pooled[g * HID + l], b = pooled[g * HID + 64 + l];
  float p0 = a * Wout[l * 2] + b * Wout[(l + 64) * 2];
  float p1 = a * Wout[l * 2 + 1] + b * Wout[(l + 64) * 2 + 1];
  #pragma unroll
  for (int d = 32; d; d >>= 1) {
    p0 += __shfl_down(p0, d, 64);
    p1 += __shfl_down(p1, d, 64);
  }
  if (l == 0) {
    out[g * 2] = p0 + bout[0];
    out[g * 2 + 1] = p1 + bout[1];
  }
}

extern "C" void kernel_launch(void* const* d_in, const int* in_sizes, int n_in,
                              void* d_out, int out_size, void* d_ws, size_t ws_size,
                              hipStream_t stream) {
  const float* x = (const float*)d_in[0];
  const int* ei = (const int*)d_in[1];
  const int* batch = (const int*)d_in[2];
  const float* Wl = (const float*)d_in[3];
  const float* Wr = (const float*)d_in[4];
  const float* bl = (const float*)d_in[5];
  const float* Wout = (const float*)d_in[6];
  const float* bout = (const float*)d_in[7];
  float* out = (float*)d_out;
  const int* srcE = ei;
  const int* dstE = ei + NE;

  // workspace layout (~31.6 MB total); h buffers have a zero pad row NN
  char* w = (char*)d_ws;
  unsigned short* hA = (unsigned short*)w; w += (size_t)(NN + 1) * HID * 2;
  unsigned short* hB = (unsigned short*)w; w += (size_t)(NN + 1) * HID * 2;
  float* invd = (float*)w;   w += (size_t)NN * 4;
  float* pooled = (float*)w; w += (size_t)NG * HID * 4;
  int* deg = (int*)w;  w += (size_t)NN * 4;
  int* cur = (int*)w;  w += (size_t)NN * 4;      // adjacent to deg (one memset)
  int* offs = (int*)w; w += (size_t)50004 * 4;
  int* csr = (int*)w;  w += (size_t)NE * 4;
  int* bsum = (int*)w; w += 256 * 4;
  unsigned short* wswh = (unsigned short*)w; w += (size_t)NL * 2 * 4 * 4096 * 2;
  unsigned short* wswl = (unsigned short*)w;

  hipMemsetAsync(deg, 0, (size_t)NN * 2 * 4, stream);
  k_deg<<<(NE + 255) / 256, 256, 0, stream>>>(dstE, deg);
  int nb = (NN + 255) / 256;
  k_scan1<<<nb, 256, 0, stream>>>(deg, offs, bsum);
  k_scan2<<<1, 256, 0, stream>>>(bsum, nb);
  k_scan3<<<nb, 256, 0, stream>>>(deg, offs, bsum, invd);
  k_fill<<<(NE + 255) / 256, 256, 0, stream>>>(srcE, dstE, offs, cur, csr);
  k_cvt<<<(NN * HID / 4 + 255) / 256, 256, 0, stream>>>(x, hA, hB);
  k_swz<<<(NL * 2 * 4 * 4096 + 255) / 256, 256, 0, stream>>>(Wl, Wr, wswh, wswl);

  unsigned short* curh = hA;
  unsigned short* nxth = hB;
  for (int l = 0; l < NL; l++) {
    k_layer<<<(NN + 63) / 64, 256, 0, stream>>>(curh, offs, csr, invd,
                                                wswh + (size_t)l * 2 * 4 * 4096,
                                                wswl + (size_t)l * 2 * 4 * 4096,
                                                bl + l * HID, nxth,
                                                (l < NL - 1) ? 1 : 0);
    unsigned short* t = curh; curh = nxth; nxth = t;
  }
  k_pool<<<NG, 128, 0, stream>>>(curh, batch, pooled);
  k_out<<<NG, 64, 0, stream>>>(pooled, Wout, bout, out);
}